// Round 1
// baseline (66.988 us; speedup 1.0000x reference)
//
#include <hip/hip_runtime.h>
#include <hip/hip_bf16.h>

#define INPUT_SIZE 128
#define NUM_REL 16
#define NODES_PER_BLOCK 8

// Kernel 1: per-node logits. L[n][r] = x[n] . att_weight[0:128, r]   (r in 0..15)
//           L[n][16+r]      = x[n] . att_weight[128:256, r]
__global__ void node_logits_kernel(const float* __restrict__ x,
                                   const float* __restrict__ w,   // (256,16) row-major
                                   float* __restrict__ L,
                                   int num_nodes) {
    __shared__ float sw[256 * NUM_REL];                 // 16 KB
    __shared__ float sx[NODES_PER_BLOCK][INPUT_SIZE];   // 4 KB

    const int tid = threadIdx.x;  // 0..255

    // Stage weights: 4096 floats = 1024 float4, 4 per thread, coalesced.
    {
        const float4* w4 = (const float4*)w;
        float4* sw4 = (float4*)sw;
        #pragma unroll
        for (int i = 0; i < 4; ++i)
            sw4[tid + i * 256] = w4[tid + i * 256];
    }

    const int node0 = blockIdx.x * NODES_PER_BLOCK;

    // Stage 8 x-rows: 1024 floats = 256 float4, 1 per thread, coalesced.
    {
        const int n = tid >> 5;        // 32 float4 per row
        const int c = tid & 31;
        const int gn = node0 + n;
        float4 v = make_float4(0.f, 0.f, 0.f, 0.f);
        if (gn < num_nodes) v = ((const float4*)x)[gn * 32 + c];
        ((float4*)sx)[tid] = v;
    }
    __syncthreads();

    const int n  = tid >> 5;   // node within block
    const int r  = tid & 31;   // 0..31 : 0..15 = src half, 16..31 = dst half
    const int gn = node0 + n;
    if (gn >= num_nodes) return;

    const int r16  = r & 15;
    const int base = (r < 16) ? 0 : (INPUT_SIZE * NUM_REL);

    float acc = 0.f;
    #pragma unroll 8
    for (int k = 0; k < INPUT_SIZE; ++k)
        acc += sx[n][k] * sw[base + k * NUM_REL + r16];

    L[gn * 32 + r] = acc;
}

// Kernel 2: per-edge gather + sigmoid + clamp. 4 edges per thread (int4/float4).
__global__ void edge_score_kernel(const int* __restrict__ ei,   // (2, E) int32
                                  const int* __restrict__ et,   // (E,) int32
                                  const float* __restrict__ L,  // (N, 32)
                                  float* __restrict__ out,
                                  int num_edges) {
    const int i = blockIdx.x * blockDim.x + threadIdx.x;  // quad index
    const int e0 = i * 4;
    if (e0 >= num_edges) return;

    const int4 s4 = ((const int4*)ei)[i];
    const int4 d4 = ((const int4*)(ei + num_edges))[i];
    const int4 t4 = ((const int4*)et)[i];

    const int s[4] = {s4.x, s4.y, s4.z, s4.w};
    const int d[4] = {d4.x, d4.y, d4.z, d4.w};
    const int t[4] = {t4.x, t4.y, t4.z, t4.w};

    float r[4];
    #pragma unroll
    for (int j = 0; j < 4; ++j) {
        const float sc = L[s[j] * 32 + t[j]] + L[d[j] * 32 + 16 + t[j]];
        float att = 1.f / (1.f + __expf(-sc));
        r[j] = fminf(fmaxf(att, 1e-5f), 0.99999f);
    }
    ((float4*)out)[i] = make_float4(r[0], r[1], r[2], r[3]);
}

// Fallback (only if ws too small): direct per-edge dot product.
__global__ void edge_direct_kernel(const float* __restrict__ x,
                                   const float* __restrict__ w,
                                   const int* __restrict__ ei,
                                   const int* __restrict__ et,
                                   float* __restrict__ out,
                                   int num_edges) {
    const int e = blockIdx.x * blockDim.x + threadIdx.x;
    if (e >= num_edges) return;
    const int s = ei[e];
    const int d = ei[num_edges + e];
    const int t = et[e];
    const float* xs = x + (size_t)s * INPUT_SIZE;
    const float* xd = x + (size_t)d * INPUT_SIZE;
    float acc = 0.f;
    #pragma unroll 4
    for (int k = 0; k < INPUT_SIZE; ++k)
        acc += xs[k] * w[k * NUM_REL + t] + xd[k] * w[(INPUT_SIZE + k) * NUM_REL + t];
    float att = 1.f / (1.f + __expf(-acc));
    out[e] = fminf(fmaxf(att, 1e-5f), 0.99999f);
}

extern "C" void kernel_launch(void* const* d_in, const int* in_sizes, int n_in,
                              void* d_out, int out_size, void* d_ws, size_t ws_size,
                              hipStream_t stream) {
    const float* x  = (const float*)d_in[0];   // (50000, 128) f32
    const float* w  = (const float*)d_in[1];   // (256, 16) f32
    const int*   ei = (const int*)d_in[2];     // (2, E) int32
    const int*   et = (const int*)d_in[3];     // (E,) int32
    float* out = (float*)d_out;

    const int num_nodes = in_sizes[0] / INPUT_SIZE;
    const int num_edges = in_sizes[3];

    const size_t ws_needed = (size_t)num_nodes * 32 * sizeof(float);

    if (ws_size >= ws_needed && (num_edges & 3) == 0) {
        float* L = (float*)d_ws;

        const int blocks1 = (num_nodes + NODES_PER_BLOCK - 1) / NODES_PER_BLOCK;
        node_logits_kernel<<<blocks1, 256, 0, stream>>>(x, w, L, num_nodes);

        const int quads   = num_edges / 4;
        const int blocks2 = (quads + 255) / 256;
        edge_score_kernel<<<blocks2, 256, 0, stream>>>(ei, et, L, out, num_edges);
    } else {
        const int blocks = (num_edges + 255) / 256;
        edge_direct_kernel<<<blocks, 256, 0, stream>>>(x, w, ei, et, out, num_edges);
    }
}

// Round 2
// 43.634 us; speedup vs baseline: 1.5352x; 1.5352x over previous
//
#include <hip/hip_runtime.h>
#include <hip/hip_fp16.h>

#define INPUT_SIZE 128
#define NUM_REL 16

// ---------------------------------------------------------------------------
// Kernel 1: per-node logit table, fp16 output.
//   L[n][r]    = x[n] . att_weight[0:128, r]      (r = 0..15, src half)
//   L[n][16+r] = x[n] . att_weight[128:256, r]    (dst half)
// Block: 256 threads = 128 nodes. Thread tile: 4 nodes x 4 relations.
//   x: read directly global->VGPR (float4); each x line is consumed by exactly
//      one wave (broadcast across its 8 rel-groups) -> no LDS staging for x.
//   w: 16 KB LDS, repacked swc[k][32] so ds_read_b128 fetches 4 relations.
//      Per instr: 8 unique addrs (rg*16B) spanning all 32 banks once -> no conflicts.
// ---------------------------------------------------------------------------
__global__ __launch_bounds__(256) void node_logits_kernel(
    const float* __restrict__ x,
    const float* __restrict__ w,     // (256,16) row-major
    __half* __restrict__ L,          // (num_nodes, 32) fp16
    int num_nodes)
{
    __shared__ float swc[128 * 32];  // swc[k*32 + r], 16 KB

    const int tid = threadIdx.x;

    // Stage + repack weights: swc[k][r] = r<16 ? w[k][r] : w[128+k][r-16]
    #pragma unroll
    for (int i = 0; i < 16; ++i) {
        const int idx = i * 256 + tid;        // 0..4095
        const int k = idx >> 5, r = idx & 31;
        swc[idx] = (r < 16) ? w[k * NUM_REL + r]
                            : w[(INPUT_SIZE + k) * NUM_REL + (r - 16)];
    }
    __syncthreads();

    const int ng = tid >> 3;                  // node group 0..31
    const int rg = tid & 7;                   // rel group  0..7
    const int node0 = blockIdx.x * 128 + ng * 4;
    const int r0 = rg * 4;

    const float4* xr[4];
    bool valid[4];
    #pragma unroll
    for (int n = 0; n < 4; ++n) {
        const int nn = node0 + n;
        valid[n] = (nn < num_nodes);
        const int cn = valid[n] ? nn : 0;     // clamp: safe read, store predicated
        xr[n] = (const float4*)(x + (size_t)cn * INPUT_SIZE);
    }

    float acc[4][4] = {};

    #pragma unroll 4
    for (int ks = 0; ks < 32; ++ks) {         // 4 k's per step
        float4 xv[4], wv[4];
        #pragma unroll
        for (int n = 0; n < 4; ++n) xv[n] = xr[n][ks];
        #pragma unroll
        for (int kk = 0; kk < 4; ++kk)
            wv[kk] = *(const float4*)&swc[(ks * 4 + kk) * 32 + r0];

        #pragma unroll
        for (int n = 0; n < 4; ++n) {
            #define FMA4(X, W) { acc[n][0] += (X) * (W).x; acc[n][1] += (X) * (W).y; \
                                 acc[n][2] += (X) * (W).z; acc[n][3] += (X) * (W).w; }
            FMA4(xv[n].x, wv[0]);
            FMA4(xv[n].y, wv[1]);
            FMA4(xv[n].z, wv[2]);
            FMA4(xv[n].w, wv[3]);
            #undef FMA4
        }
    }

    #pragma unroll
    for (int n = 0; n < 4; ++n) {
        if (!valid[n]) continue;
        union { __half2 h2[2]; uint2 u; } pk;
        pk.h2[0] = __floats2half2_rn(acc[n][0], acc[n][1]);
        pk.h2[1] = __floats2half2_rn(acc[n][2], acc[n][3]);
        *(uint2*)(L + (size_t)(node0 + n) * 32 + r0) = pk.u;   // 8B aligned
    }
}

// ---------------------------------------------------------------------------
// Kernel 2: per-edge gather + sigmoid + clamp. 4 edges/thread.
// fp16 table = 3.2 MB -> L2-resident; src+dst halves of a node share one 64B line.
// ---------------------------------------------------------------------------
__global__ __launch_bounds__(256) void edge_score_kernel(
    const int* __restrict__ ei,      // (2, E) int32
    const int* __restrict__ et,      // (E,) int32
    const __half* __restrict__ L,    // (N, 32) fp16
    float* __restrict__ out,
    int num_edges)
{
    const int i = blockIdx.x * blockDim.x + threadIdx.x;   // quad index
    if (i * 4 >= num_edges) return;

    const int4 s4 = ((const int4*)ei)[i];
    const int4 d4 = ((const int4*)(ei + num_edges))[i];
    const int4 t4 = ((const int4*)et)[i];

    const int s[4] = {s4.x, s4.y, s4.z, s4.w};
    const int d[4] = {d4.x, d4.y, d4.z, d4.w};
    const int t[4] = {t4.x, t4.y, t4.z, t4.w};

    float r[4];
    #pragma unroll
    for (int j = 0; j < 4; ++j) {
        const float sc = __half2float(L[(size_t)s[j] * 32 + t[j]])
                       + __half2float(L[(size_t)d[j] * 32 + 16 + t[j]]);
        const float att = 1.f / (1.f + __expf(-sc));
        r[j] = fminf(fmaxf(att, 1e-5f), 0.99999f);
    }
    ((float4*)out)[i] = make_float4(r[0], r[1], r[2], r[3]);
}

// Fallback: direct per-edge dot product in f32 (no workspace table).
__global__ void edge_direct_kernel(const float* __restrict__ x,
                                   const float* __restrict__ w,
                                   const int* __restrict__ ei,
                                   const int* __restrict__ et,
                                   float* __restrict__ out,
                                   int num_edges) {
    const int e = blockIdx.x * blockDim.x + threadIdx.x;
    if (e >= num_edges) return;
    const int s = ei[e];
    const int d = ei[num_edges + e];
    const int t = et[e];
    const float* xs = x + (size_t)s * INPUT_SIZE;
    const float* xd = x + (size_t)d * INPUT_SIZE;
    float acc = 0.f;
    #pragma unroll 4
    for (int k = 0; k < INPUT_SIZE; ++k)
        acc += xs[k] * w[k * NUM_REL + t] + xd[k] * w[(INPUT_SIZE + k) * NUM_REL + t];
    const float att = 1.f / (1.f + __expf(-acc));
    out[e] = fminf(fmaxf(att, 1e-5f), 0.99999f);
}

extern "C" void kernel_launch(void* const* d_in, const int* in_sizes, int n_in,
                              void* d_out, int out_size, void* d_ws, size_t ws_size,
                              hipStream_t stream) {
    const float* x  = (const float*)d_in[0];   // (50000, 128) f32
    const float* w  = (const float*)d_in[1];   // (256, 16) f32
    const int*   ei = (const int*)d_in[2];     // (2, E) int32
    const int*   et = (const int*)d_in[3];     // (E,) int32
    float* out = (float*)d_out;

    const int num_nodes = in_sizes[0] / INPUT_SIZE;
    const int num_edges = in_sizes[3];

    const size_t ws_needed = (size_t)num_nodes * 32 * sizeof(__half);

    if (ws_size >= ws_needed && (num_edges & 3) == 0) {
        __half* L = (__half*)d_ws;

        const int blocks1 = (num_nodes + 127) / 128;
        node_logits_kernel<<<blocks1, 256, 0, stream>>>(x, w, L, num_nodes);

        const int quads   = num_edges / 4;
        const int blocks2 = (quads + 255) / 256;
        edge_score_kernel<<<blocks2, 256, 0, stream>>>(ei, et, L, out, num_edges);
    } else {
        const int blocks = (num_edges + 255) / 256;
        edge_direct_kernel<<<blocks, 256, 0, stream>>>(x, w, ei, et, out, num_edges);
    }
}